// Round 6
// baseline (26.945 us; speedup 1.0000x reference)
//
#include <hip/hip_runtime.h>

// Quanvolution, fused: every block recomputes the 162-coefficient observable
// tensor T from the weights in LDS, then contracts per-pixel.
//   z_q(f0..f3) = sum_{p in {I,Y,Z}^4} T_q[p] * prod_k v_k(p_k),
//   v_k = (1, -sin f_k, cos f_k)   (RX(f)|0> has <X>=0).
// T_q from 16 basis-state sims of the data-independent entangler U:
//   M_q[r,r'] = <r,0000|U^dag Z_q U|r',0000> (Hermitian -> 136 pairs)
//   -> Pauli transform -> T_q[81] (1/3 channel-mean folded in).
//
// Phase A mapping (one basis column per wave, 16 waves):
//   qubits 0,1 = local bits (4 complex amps/lane), qubits 2..7 = lane bits 0..5.

namespace {

// ---- 64-lane wave-sim helpers (4 local amps) ----

__device__ __forceinline__ void rx_l0(float (&sr)[4], float (&si)[4], float c, float s) {
    float nr0 = c*sr[0] + s*si[1], ni0 = c*si[0] - s*sr[1];
    float nr1 = c*sr[1] + s*si[0], ni1 = c*si[1] - s*sr[0];
    float nr2 = c*sr[2] + s*si[3], ni2 = c*si[2] - s*sr[3];
    float nr3 = c*sr[3] + s*si[2], ni3 = c*si[3] - s*sr[2];
    sr[0]=nr0; si[0]=ni0; sr[1]=nr1; si[1]=ni1;
    sr[2]=nr2; si[2]=ni2; sr[3]=nr3; si[3]=ni3;
}

__device__ __forceinline__ void rx_l1(float (&sr)[4], float (&si)[4], float c, float s) {
    float nr0 = c*sr[0] + s*si[2], ni0 = c*si[0] - s*sr[2];
    float nr2 = c*sr[2] + s*si[0], ni2 = c*si[2] - s*sr[0];
    float nr1 = c*sr[1] + s*si[3], ni1 = c*si[1] - s*sr[3];
    float nr3 = c*sr[3] + s*si[1], ni3 = c*si[3] - s*sr[1];
    sr[0]=nr0; si[0]=ni0; sr[1]=nr1; si[1]=ni1;
    sr[2]=nr2; si[2]=ni2; sr[3]=nr3; si[3]=ni3;
}

__device__ __forceinline__ void rx_lane4(float (&sr)[4], float (&si)[4], float c, float s, int mask) {
#pragma unroll
    for (int r = 0; r < 4; ++r) {
        float orr = __shfl_xor(sr[r], mask, 64);
        float oii = __shfl_xor(si[r], mask, 64);
        sr[r] = c*sr[r] + s*oii;
        si[r] = c*si[r] - s*orr;
    }
}

// entangler, one column per 64-lane wave (verified round-1 mapping)
__device__ __forceinline__ void entangler64(float (&sr)[4], float (&si)[4],
                                            const float* __restrict__ w, int lane) {
    float c, s;
#pragma unroll
    for (int l = 0; l < 2; ++l) {
        __sincosf(0.5f*w[l*8+0], &s, &c); rx_l0(sr, si, c, s);
        __sincosf(0.5f*w[l*8+1], &s, &c); rx_l1(sr, si, c, s);
#pragma unroll
        for (int q = 2; q < 8; ++q) {
            __sincosf(0.5f*w[l*8+q], &s, &c);
            rx_lane4(sr, si, c, s, 1 << (q-2));
        }

        // CNOT(0,1): amps with b0=1 flip b1 -> swap r1<->r3
        { float tr=sr[1], ti=si[1]; sr[1]=sr[3]; si[1]=si[3]; sr[3]=tr; si[3]=ti; }

        // CNOT(1,2): amps with b1=1 (r=2,3) flip lane-bit0
        sr[2] = __shfl_xor(sr[2], 1, 64); si[2] = __shfl_xor(si[2], 1, 64);
        sr[3] = __shfl_xor(sr[3], 1, 64); si[3] = __shfl_xor(si[3], 1, 64);

        // CNOT(q,q+1), q=2..6: control lane-bit (q-2), target lane-bit (q-1)
#pragma unroll
        for (int q = 2; q <= 6; ++q) {
            const int mt = 1 << (q-1);
            const bool ctrl = (lane >> (q-2)) & 1;
#pragma unroll
            for (int r = 0; r < 4; ++r) {
                float orr = __shfl_xor(sr[r], mt, 64);
                float oii = __shfl_xor(si[r], mt, 64);
                sr[r] = ctrl ? orr : sr[r];
                si[r] = ctrl ? oii : si[r];
            }
        }

        // CNOT(7,0): lanes with bit5=1 swap (r0<->r1),(r2<->r3)
        {
            const bool ctrl = (lane >> 5) & 1;
            float a0 = ctrl ? sr[1] : sr[0], b0 = ctrl ? si[1] : si[0];
            float a1 = ctrl ? sr[0] : sr[1], b1 = ctrl ? si[0] : si[1];
            float a2 = ctrl ? sr[3] : sr[2], b2 = ctrl ? si[3] : si[2];
            float a3 = ctrl ? sr[2] : sr[3], b3 = ctrl ? si[2] : si[3];
            sr[0]=a0; si[0]=b0; sr[1]=a1; si[1]=b1;
            sr[2]=a2; si[2]=b2; sr[3]=a3; si[3]=b3;
        }
    }
}

__device__ __forceinline__ int uidx(int n, int g) { return n*16 + g + (n>>4); }

__device__ __forceinline__ void tri_decode(int t, int& rr, int& rp) {
    int r = 0, rem = t;
    while (rem >= 16 - r) { rem -= 16 - r; ++r; }
    rr = r; rp = r + rem;
}

__device__ __forceinline__ int ilv(int bra, int ket) {
    int idx = 0;
#pragma unroll
    for (int k = 0; k < 4; ++k)
        idx |= (((bra>>k)&1) << (2*k+1)) | (((ket>>k)&1) << (2*k));
    return idx;
}

} // namespace

#define NPIX (8*39*39)   // 12168
#define BLK  1024
#define PPB  512
#define NBLK ((NPIX + PPB - 1) / PPB)   // 24

__global__ __launch_bounds__(1024) void quanv_fused(
    const float* __restrict__ x,   // (8,3,40,40)
    const float* __restrict__ w,   // (2,8)
    float* __restrict__ out)       // (8,2,39,39)
{
    __shared__ float2 U[16*256 + 16];    // U[n][g], padded
    __shared__ float2 XA[2][256];
    __shared__ float2 XB[2][256];
    __shared__ float2 PB[4][2][136];     // [quarter][q][pair] Gram partials
    __shared__ __align__(16) float Tp[216];  // [q][27][4] = (t0,t1,t2,pad)

    const int tid  = (int)threadIdx.x;
    const int lane = tid & 63;
    const int wv   = tid >> 6;            // wave index = basis column g

    // ---- pixel/q decode + loads + embedding sincos (all before setup) ----
    const int half = tid >> 9;            // output qubit q for contraction
    const int gpix = (int)blockIdx.x * PPB + (tid & 511);
    const int pid  = (gpix < NPIX) ? gpix : (NPIX - 1);
    const int j  = pid % 39;
    const int t2 = pid / 39;
    const int i  = t2 % 39;
    const int b  = t2 / 39;

    float vy[3][4], vz[3][4];
#pragma unroll
    for (int c = 0; c < 3; ++c) {
        const float* xp = x + (((b*3 + c)*40) + i)*40 + j;
        const float f0 = xp[0], f1 = xp[1], f2 = xp[40], f3 = xp[41];
        float s, co;
        __sincosf(f0, &s, &co); vy[c][0] = -s; vz[c][0] = co;
        __sincosf(f1, &s, &co); vy[c][1] = -s; vz[c][1] = co;
        __sincosf(f2, &s, &co); vy[c][2] = -s; vz[c][2] = co;
        __sincosf(f3, &s, &co); vy[c][3] = -s; vz[c][3] = co;
    }

    // ---- Phase A: 16 basis-state sims, one column per wave ----
    {
        // |g>: qubits 0,1 = g&3 (local r), qubits 2,3 = g>>2 (lane bits 0,1)
        float sr[4], si[4];
        const int lane0 = (wv >> 2) & 3;
        const int r0    = wv & 3;
#pragma unroll
        for (int r = 0; r < 4; ++r) {
            sr[r] = (lane == lane0 && r == r0) ? 1.f : 0.f;
            si[r] = 0.f;
        }
        entangler64(sr, si, w, lane);
#pragma unroll
        for (int r = 0; r < 4; ++r) {
            const int n = (lane << 2) | r;
            U[uidx(n, wv)] = make_float2(sr[r], si[r]);
        }
    }
    __syncthreads();

    // ---- Phase B: Hermitian Gram partials, 136 pairs x 4-way n-split ----
    if (tid < 544) {
        const int t = tid >> 2, quarter = tid & 3;
        int rr, rp; tri_decode(t, rr, rp);
        float2 a0={0,0}, a1={0,0}, a2={0,0}, a3={0,0};
        const int n0 = quarter * 64;
        for (int n = n0; n < n0 + 64; n += 4) {
#pragma unroll
            for (int cls = 0; cls < 4; ++cls) {
                const float2 ur = U[uidx(n+cls, rr)];
                const float2 up = U[uidx(n+cls, rp)];
                const float cre = ur.x*up.x + ur.y*up.y;
                const float cim = ur.x*up.y - ur.y*up.x;
                if      (cls==0) { a0.x += cre; a0.y += cim; }
                else if (cls==1) { a1.x += cre; a1.y += cim; }
                else if (cls==2) { a2.x += cre; a2.y += cim; }
                else             { a3.x += cre; a3.y += cim; }
            }
        }
        PB[quarter][0][t] = make_float2((a0.x - a1.x) + (a2.x - a3.x),
                                        (a0.y - a1.y) + (a2.y - a3.y));
        PB[quarter][1][t] = make_float2((a0.x + a1.x) - (a2.x + a3.x),
                                        (a0.y + a1.y) - (a2.y + a3.y));
    }
    __syncthreads();

    // ---- combine quarters + Hermitian mirror + bit-interleave ----
    if (tid < 136) {
        int rr, rp; tri_decode(tid, rr, rp);
        const int idx  = ilv(rr, rp);
        const int idxT = ilv(rp, rr);
#pragma unroll
        for (int q = 0; q < 2; ++q) {
            float2 m = PB[0][q][tid];
            m.x += PB[1][q][tid].x + PB[2][q][tid].x + PB[3][q][tid].x;
            m.y += PB[1][q][tid].y + PB[2][q][tid].y + PB[3][q][tid].y;
            XA[q][idxT] = make_float2(m.x, -m.y);
            XA[q][idx]  = m;
        }
    }
    __syncthreads();

    // ---- Phase C: Pauli transform along 4 qubit axes ----
    float2 (*A)[256] = XA;
    float2 (*B)[256] = XB;
    for (int k = 0; k < 4; ++k) {
        if (tid < 128) {
            const int q = tid >> 6, quad = tid & 63;
            const int st = 1 << (2*k);
            const int ml = st - 1;
            const int base = (quad & ml) | ((quad & ~ml) << 2);
            const float2 i00 = A[q][base],      i01 = A[q][base+st];
            const float2 i10 = A[q][base+2*st], i11 = A[q][base+3*st];
            B[q][base]      = make_float2(0.5f*(i00.x+i11.x), 0.5f*(i00.y+i11.y)); // I
            B[q][base+st]   = make_float2(0.5f*(i01.x+i10.x), 0.5f*(i01.y+i10.y)); // X
            B[q][base+2*st] = make_float2(-0.5f*(i01.y-i10.y), 0.5f*(i01.x-i10.x)); // Y
            B[q][base+3*st] = make_float2(0.5f*(i00.x-i11.x), 0.5f*(i00.y-i11.y)); // Z
        }
        __syncthreads();
        float2 (*t)[256] = A; A = B; B = t;
    }

    // ---- Phase D: extract {I,Y,Z}^4 real coefficients (1/3 folded) ----
    if (tid < 162) {
        const int q = tid / 81, u = tid % 81;
        const int i0 = u % 3, i1 = (u/3) % 3, i2 = (u/9) % 3, i3 = u / 27;
        const int p0 = (i0==0)?0:(i0+1);
        const int p1 = (i1==0)?0:(i1+1);
        const int p2 = (i2==0)?0:(i2+1);
        const int p3 = (i3==0)?0:(i3+1);
        const int idx = p0 | (p1<<2) | (p2<<4) | (p3<<6);
        Tp[q*108 + (u/3)*4 + i0] = A[q][idx].x * (1.f/3.f);
    }
    __syncthreads();

    // ---- contraction: one (pixel, q) per thread ----
    if (gpix < NPIX) {
        float a3[3] = {0.f, 0.f, 0.f};
#pragma unroll
        for (int i3 = 0; i3 < 3; ++i3) {
            float a2[3] = {0.f, 0.f, 0.f};
#pragma unroll
            for (int i2 = 0; i2 < 3; ++i2) {
                float a1[3] = {0.f, 0.f, 0.f};
#pragma unroll
                for (int i1 = 0; i1 < 3; ++i1) {
                    const float4 tv = *reinterpret_cast<const float4*>(
                        &Tp[half*108 + ((i3*3 + i2)*3 + i1)*4]);
#pragma unroll
                    for (int c = 0; c < 3; ++c) {
                        const float s = fmaf(tv.z, vz[c][0], fmaf(tv.y, vy[c][0], tv.x));
                        if      (i1 == 0) a1[c] += s;
                        else if (i1 == 1) a1[c] = fmaf(s, vy[c][1], a1[c]);
                        else              a1[c] = fmaf(s, vz[c][1], a1[c]);
                    }
                }
#pragma unroll
                for (int c = 0; c < 3; ++c) {
                    if      (i2 == 0) a2[c] += a1[c];
                    else if (i2 == 1) a2[c] = fmaf(a1[c], vy[c][2], a2[c]);
                    else              a2[c] = fmaf(a1[c], vz[c][2], a2[c]);
                }
            }
#pragma unroll
            for (int c = 0; c < 3; ++c) {
                if      (i3 == 0) a3[c] += a2[c];
                else if (i3 == 1) a3[c] = fmaf(a2[c], vy[c][3], a3[c]);
                else              a3[c] = fmaf(a2[c], vz[c][3], a3[c]);
            }
        }

        out[((b*2 + half)*39 + i)*39 + j] = a3[0] + a3[1] + a3[2];
    }
}

extern "C" void kernel_launch(void* const* d_in, const int* in_sizes, int n_in,
                              void* d_out, int out_size, void* d_ws, size_t ws_size,
                              hipStream_t stream) {
    const float* x = (const float*)d_in[0];
    const float* w = (const float*)d_in[1];
    float* out = (float*)d_out;

    quanv_fused<<<NBLK, BLK, 0, stream>>>(x, w, out);
}

// Round 7
// 20.466 us; speedup vs baseline: 1.3166x; 1.3166x over previous
//
#include <hip/hip_runtime.h>

// Quanvolution, fused: every block recomputes the 162-coefficient observable
// tensor T from the weights in LDS, then contracts per-pixel.
//   z_q(f0..f3) = sum_{p in {I,Y,Z}^4} T_q[p] * prod_k v_k(p_k),
//   v_k = (1, -sin f_k, cos f_k)   (RX(f)|0> has <X>=0).
// T_q from 16 basis-state sims of the data-independent entangler U:
//   M_q[r,r'] = <r,0000|U^dag Z_q U|r',0000> (Hermitian -> 136 pairs)
//   -> Pauli transform -> T_q[81] (1/3 channel-mean folded in).
//
// Phase A mapping (measured-best, round 5): qubits 0..3 local (16 amps/lane),
// qubits 4..7 = lane bits 0..3; 4 basis columns per wave, waves 0..3.
// Waves 4..15 overlap their embedding sincos with Phase A.

namespace {

template<int M>
__device__ __forceinline__ void rx_local(float (&sr)[16], float (&si)[16], float c, float s) {
#pragma unroll
    for (int r = 0; r < 16; ++r) {
        if (r & M) continue;
        const int a = r, b = r | M;
        float nra = c*sr[a] + s*si[b], nia = c*si[a] - s*sr[b];
        float nrb = c*sr[b] + s*si[a], nib = c*si[b] - s*sr[a];
        sr[a]=nra; si[a]=nia; sr[b]=nrb; si[b]=nib;
    }
}

__device__ __forceinline__ void rx_lane16(float (&sr)[16], float (&si)[16], float c, float s, int mask) {
#pragma unroll
    for (int r = 0; r < 16; ++r) {
        float orr = __shfl_xor(sr[r], mask, 64);
        float oii = __shfl_xor(si[r], mask, 64);
        sr[r] = c*sr[r] + s*oii;
        si[r] = c*si[r] - s*orr;
    }
}

template<int C, int T>
__device__ __forceinline__ void cnot_ll(float (&sr)[16], float (&si)[16]) {
#pragma unroll
    for (int r = 0; r < 16; ++r) {
        if (!(r & C) || (r & T)) continue;
        const int a = r, b = r ^ T;
        float tr=sr[a], ti=si[a];
        sr[a]=sr[b]; si[a]=si[b];
        sr[b]=tr;    si[b]=ti;
    }
}

__device__ __forceinline__ void entangler(float (&sr)[16], float (&si)[16],
                                          const float* __restrict__ w, int lane) {
    float c, s;
#pragma unroll 1   // keep code size down (icache); loop body is large
    for (int l = 0; l < 2; ++l) {
        __sincosf(0.5f*w[l*8+0], &s, &c); rx_local<1>(sr, si, c, s);
        __sincosf(0.5f*w[l*8+1], &s, &c); rx_local<2>(sr, si, c, s);
        __sincosf(0.5f*w[l*8+2], &s, &c); rx_local<4>(sr, si, c, s);
        __sincosf(0.5f*w[l*8+3], &s, &c); rx_local<8>(sr, si, c, s);
        __sincosf(0.5f*w[l*8+4], &s, &c); rx_lane16(sr, si, c, s, 1);
        __sincosf(0.5f*w[l*8+5], &s, &c); rx_lane16(sr, si, c, s, 2);
        __sincosf(0.5f*w[l*8+6], &s, &c); rx_lane16(sr, si, c, s, 4);
        __sincosf(0.5f*w[l*8+7], &s, &c); rx_lane16(sr, si, c, s, 8);

        cnot_ll<1,2>(sr, si);   // (0,1)
        cnot_ll<2,4>(sr, si);   // (1,2)
        cnot_ll<4,8>(sr, si);   // (2,3)
#pragma unroll
        for (int r = 8; r < 16; ++r) {           // (3,4)
            sr[r] = __shfl_xor(sr[r], 1, 64);
            si[r] = __shfl_xor(si[r], 1, 64);
        }
#pragma unroll
        for (int qq = 0; qq < 3; ++qq) {         // (4,5),(5,6),(6,7)
            const int mt = 2 << qq;
            const bool ctrl = (lane >> qq) & 1;
#pragma unroll
            for (int r = 0; r < 16; ++r) {
                float orr = __shfl_xor(sr[r], mt, 64);
                float oii = __shfl_xor(si[r], mt, 64);
                sr[r] = ctrl ? orr : sr[r];
                si[r] = ctrl ? oii : si[r];
            }
        }
        {                                         // (7,0)
            const bool c7 = (lane >> 3) & 1;
#pragma unroll
            for (int r = 0; r < 16; r += 2) {
                float ar = c7 ? sr[r+1] : sr[r];
                float ai = c7 ? si[r+1] : si[r];
                float br = c7 ? sr[r]   : sr[r+1];
                float bi = c7 ? si[r]   : si[r+1];
                sr[r]=ar; si[r]=ai; sr[r+1]=br; si[r+1]=bi;
            }
        }
    }
}

__device__ __forceinline__ int uidx(int n, int g) { return n*16 + g + (n>>4); }

__device__ __forceinline__ void tri_decode(int t, int& rr, int& rp) {
    int r = 0, rem = t;
    while (rem >= 16 - r) { rem -= 16 - r; ++r; }
    rr = r; rp = r + rem;
}

__device__ __forceinline__ int ilv(int bra, int ket) {
    int idx = 0;
#pragma unroll
    for (int k = 0; k < 4; ++k)
        idx |= (((bra>>k)&1) << (2*k+1)) | (((ket>>k)&1) << (2*k));
    return idx;
}

// embedding vectors from the 12 loaded patch values
__device__ __forceinline__ void emb_sincos(const float (&f)[12],
                                           float (&vy)[3][4], float (&vz)[3][4]) {
#pragma unroll
    for (int c = 0; c < 3; ++c) {
#pragma unroll
        for (int k = 0; k < 4; ++k) {
            float s, co;
            __sincosf(f[c*4+k], &s, &co);
            vy[c][k] = -s; vz[c][k] = co;
        }
    }
}

} // namespace

#define NPIX (8*39*39)   // 12168
#define BLK  1024
#define PPB  512
#define NBLK ((NPIX + PPB - 1) / PPB)   // 24

__global__ __launch_bounds__(1024) void quanv_fused(
    const float* __restrict__ x,   // (8,3,40,40)
    const float* __restrict__ w,   // (2,8)
    float* __restrict__ out)       // (8,2,39,39)
{
    __shared__ float2 U[16*256 + 16];    // U[n][g], padded
    __shared__ float2 XA[2][256];
    __shared__ float2 XB[2][256];
    __shared__ float2 PB[4][2][136];     // [quarter][q][pair] Gram partials
    __shared__ __align__(16) float Tp[216];  // [q][27][4] = (t0,t1,t2,pad)

    const int tid  = (int)threadIdx.x;
    const int lane = tid & 63;

    // ---- pixel/q decode; issue loads early (latency hides under setup) ----
    const int half = tid >> 9;            // output qubit q for contraction
    const int gpix = (int)blockIdx.x * PPB + (tid & 511);
    const int pid  = (gpix < NPIX) ? gpix : (NPIX - 1);
    const int j  = pid % 39;
    const int t2 = pid / 39;
    const int i  = t2 % 39;
    const int b  = t2 / 39;

    float f[12];
#pragma unroll
    for (int c = 0; c < 3; ++c) {
        const float* xp = x + (((b*3 + c)*40) + i)*40 + j;
        f[c*4+0] = xp[0];  f[c*4+1] = xp[1];
        f[c*4+2] = xp[40]; f[c*4+3] = xp[41];
    }

    float vy[3][4], vz[3][4];

    // ---- Phase A: 16 basis-state sims on waves 0-3; other waves do their
    // ---- embedding sincos in the idle slot ----
    if (tid < 256) {
        const int g = (tid >> 6) * 4 + (lane >> 4);
        float sr[16], si[16];
#pragma unroll
        for (int r = 0; r < 16; ++r) {
            sr[r] = (((lane & 15) == 0) && (r == g)) ? 1.f : 0.f;
            si[r] = 0.f;
        }
        entangler(sr, si, w, lane);
#pragma unroll
        for (int r = 0; r < 16; ++r) {
            const int n = ((lane & 15) << 4) | r;
            U[uidx(n, g)] = make_float2(sr[r], si[r]);
        }
    } else {
        emb_sincos(f, vy, vz);
    }
    __syncthreads();

    // ---- Phase B: Hermitian Gram partials, 136 pairs x 4-way n-split ----
    if (tid < 544) {
        const int t = tid >> 2, quarter = tid & 3;
        int rr, rp; tri_decode(t, rr, rp);
        float2 a0={0,0}, a1={0,0}, a2={0,0}, a3={0,0};
        const int n0 = quarter * 64;
        for (int n = n0; n < n0 + 64; n += 4) {
#pragma unroll
            for (int cls = 0; cls < 4; ++cls) {
                const float2 ur = U[uidx(n+cls, rr)];
                const float2 up = U[uidx(n+cls, rp)];
                const float cre = ur.x*up.x + ur.y*up.y;
                const float cim = ur.x*up.y - ur.y*up.x;
                if      (cls==0) { a0.x += cre; a0.y += cim; }
                else if (cls==1) { a1.x += cre; a1.y += cim; }
                else if (cls==2) { a2.x += cre; a2.y += cim; }
                else             { a3.x += cre; a3.y += cim; }
            }
        }
        PB[quarter][0][t] = make_float2((a0.x - a1.x) + (a2.x - a3.x),
                                        (a0.y - a1.y) + (a2.y - a3.y));
        PB[quarter][1][t] = make_float2((a0.x + a1.x) - (a2.x + a3.x),
                                        (a0.y + a1.y) - (a2.y + a3.y));
    }
    __syncthreads();

    // ---- combine quarters + Hermitian mirror + bit-interleave ----
    if (tid < 136) {
        int rr, rp; tri_decode(tid, rr, rp);
        const int idx  = ilv(rr, rp);
        const int idxT = ilv(rp, rr);
#pragma unroll
        for (int q = 0; q < 2; ++q) {
            float2 m = PB[0][q][tid];
            m.x += PB[1][q][tid].x + PB[2][q][tid].x + PB[3][q][tid].x;
            m.y += PB[1][q][tid].y + PB[2][q][tid].y + PB[3][q][tid].y;
            XA[q][idxT] = make_float2(m.x, -m.y);
            XA[q][idx]  = m;
        }
    }
    __syncthreads();

    // ---- Phase C: Pauli transform along 4 qubit axes ----
    float2 (*A)[256] = XA;
    float2 (*B)[256] = XB;
    for (int k = 0; k < 4; ++k) {
        if (tid < 128) {
            const int q = tid >> 6, quad = tid & 63;
            const int st = 1 << (2*k);
            const int ml = st - 1;
            const int base = (quad & ml) | ((quad & ~ml) << 2);
            const float2 i00 = A[q][base],      i01 = A[q][base+st];
            const float2 i10 = A[q][base+2*st], i11 = A[q][base+3*st];
            B[q][base]      = make_float2(0.5f*(i00.x+i11.x), 0.5f*(i00.y+i11.y)); // I
            B[q][base+st]   = make_float2(0.5f*(i01.x+i10.x), 0.5f*(i01.y+i10.y)); // X
            B[q][base+2*st] = make_float2(-0.5f*(i01.y-i10.y), 0.5f*(i01.x-i10.x)); // Y
            B[q][base+3*st] = make_float2(0.5f*(i00.x-i11.x), 0.5f*(i00.y-i11.y)); // Z
        }
        __syncthreads();
        float2 (*t)[256] = A; A = B; B = t;
    }

    // ---- Phase D: extract {I,Y,Z}^4 real coefficients (1/3 folded) ----
    if (tid < 162) {
        const int q = tid / 81, u = tid % 81;
        const int i0 = u % 3, i1 = (u/3) % 3, i2 = (u/9) % 3, i3 = u / 27;
        const int p0 = (i0==0)?0:(i0+1);
        const int p1 = (i1==0)?0:(i1+1);
        const int p2 = (i2==0)?0:(i2+1);
        const int p3 = (i3==0)?0:(i3+1);
        const int idx = p0 | (p1<<2) | (p2<<4) | (p3<<6);
        Tp[q*108 + (u/3)*4 + i0] = A[q][idx].x * (1.f/3.f);
    }
    __syncthreads();

    // ---- contraction: one (pixel, q) per thread ----
    if (gpix < NPIX) {
        if (tid < 256) emb_sincos(f, vy, vz);   // waves 0-3 do theirs now

        float a3[3] = {0.f, 0.f, 0.f};
#pragma unroll
        for (int i3 = 0; i3 < 3; ++i3) {
            float a2[3] = {0.f, 0.f, 0.f};
#pragma unroll
            for (int i2 = 0; i2 < 3; ++i2) {
                float a1[3] = {0.f, 0.f, 0.f};
#pragma unroll
                for (int i1 = 0; i1 < 3; ++i1) {
                    const float4 tv = *reinterpret_cast<const float4*>(
                        &Tp[half*108 + ((i3*3 + i2)*3 + i1)*4]);
#pragma unroll
                    for (int c = 0; c < 3; ++c) {
                        const float s = fmaf(tv.z, vz[c][0], fmaf(tv.y, vy[c][0], tv.x));
                        if      (i1 == 0) a1[c] += s;
                        else if (i1 == 1) a1[c] = fmaf(s, vy[c][1], a1[c]);
                        else              a1[c] = fmaf(s, vz[c][1], a1[c]);
                    }
                }
#pragma unroll
                for (int c = 0; c < 3; ++c) {
                    if      (i2 == 0) a2[c] += a1[c];
                    else if (i2 == 1) a2[c] = fmaf(a1[c], vy[c][2], a2[c]);
                    else              a2[c] = fmaf(a1[c], vz[c][2], a2[c]);
                }
            }
#pragma unroll
            for (int c = 0; c < 3; ++c) {
                if      (i3 == 0) a3[c] += a2[c];
                else if (i3 == 1) a3[c] = fmaf(a2[c], vy[c][3], a3[c]);
                else              a3[c] = fmaf(a2[c], vz[c][3], a3[c]);
            }
        }

        out[((b*2 + half)*39 + i)*39 + j] = a3[0] + a3[1] + a3[2];
    }
}

extern "C" void kernel_launch(void* const* d_in, const int* in_sizes, int n_in,
                              void* d_out, int out_size, void* d_ws, size_t ws_size,
                              hipStream_t stream) {
    const float* x = (const float*)d_in[0];
    const float* w = (const float*)d_in[1];
    float* out = (float*)d_out;

    quanv_fused<<<NBLK, BLK, 0, stream>>>(x, w, out);
}